// Round 3
// baseline (118.300 us; speedup 1.0000x reference)
//
#include <hip/hip_runtime.h>
#include <hip/hip_cooperative_groups.h>

namespace cg = cooperative_groups;

#define Bn 32
#define Ln 4096
#define GROUPn 4
#define NFG (Bn / GROUPn)
#define EPSf 1e-8f
#define JS_EPSf 1e-7f
#define NBLK 512
#define NTHR 256
#define NPAIR 496   // 32*31/2

// Block-wide sum reduction. Valid result in thread 0. Uses sm[4].
// Caller must __syncthreads() between consecutive uses.
__device__ __forceinline__ float blockReduceSum(float v, float* sm) {
    #pragma unroll
    for (int off = 32; off > 0; off >>= 1)
        v += __shfl_down(v, off, 64);
    int lane = threadIdx.x & 63;
    int wid  = threadIdx.x >> 6;
    if (lane == 0) sm[wid] = v;
    __syncthreads();
    v = (threadIdx.x < (NTHR >> 6)) ? sm[threadIdx.x] : 0.0f;
    if (wid == 0) {
        #pragma unroll
        for (int off = 32; off > 0; off >>= 1)
            v += __shfl_down(v, off, 64);
    }
    return v;
}

__device__ __forceinline__ int argmax4(float4 y) {
    int lbl = 0; float best = y.x;
    if (y.y > best) { best = y.y; lbl = 1; }
    if (y.z > best) { best = y.z; lbl = 2; }
    if (y.w > best) { best = y.w; lbl = 3; }
    return lbl;
}

// Single cooperative kernel, 512 blocks x 256 threads = exactly B*L threads.
// Phase A: per-row CE + precompute H (sum p*log(p+eps)), palt, label byte.
// grid.sync()
// Phase B: R2 from precomputed arrays; pairwise JS using H identity:
//   kl_pm+kl_qm = H_i + H_j - sum_c (p+q)*log(0.5*(p+q)+eps)
//   sum_ij w_ij*js_ij = sum_{i<j} (w_ij+w_ji)*js_ij  (js symmetric, diag 0)
// grid.sync()
// Phase C: block 0 reduces per-block partials, writes the 4 outputs.
__global__ __launch_bounds__(NTHR, 2) void imp_coop(
    const float* __restrict__ logits,
    const float* __restrict__ prob,
    const float* __restrict__ y_true,
    const float* __restrict__ y_evo,
    float* __restrict__ H,            // [B*L]
    float* __restrict__ palt,         // [B*L]
    unsigned char* __restrict__ lbl,  // [B*L]
    float* __restrict__ pce,          // [NBLK]
    float* __restrict__ pr2,          // [NBLK]
    float* __restrict__ pevo,         // [NBLK]
    float* __restrict__ out)
{
    __shared__ float sm[4];
    cg::grid_group grid = cg::this_grid();
    const int tid = blockIdx.x * NTHR + threadIdx.x;   // 0 .. B*L-1

    // ---- Phase A: one row per thread ----
    float ce;
    {
        float4 y = ((const float4*)y_true)[tid];
        float4 x = ((const float4*)logits)[tid];
        float4 p = ((const float4*)prob)[tid];
        int l = argmax4(y);
        float mx = fmaxf(fmaxf(x.x, x.y), fmaxf(x.z, x.w));
        float se = __expf(x.x - mx) + __expf(x.y - mx) +
                   __expf(x.z - mx) + __expf(x.w - mx);
        float xl = (l == 0) ? x.x : (l == 1) ? x.y : (l == 2) ? x.z : x.w;
        ce = (mx + __logf(se)) - xl;            // -log_softmax(x)[label]
        H[tid] = p.x * __logf(p.x + JS_EPSf) + p.y * __logf(p.y + JS_EPSf) +
                 p.z * __logf(p.z + JS_EPSf) + p.w * __logf(p.w + JS_EPSf);
        palt[tid] = p.y + p.z + p.w;
        lbl[tid] = (unsigned char)l;
    }

    grid.sync();

    // ---- Phase B: R2 (first NFG*L threads, one item each) ----
    float r2 = 0.0f;
    if (tid < NFG * Ln) {
        int g = tid >> 12;              // / Ln
        int l = tid & (Ln - 1);
        int cnt = 0;
        float pa[GROUPn];
        #pragma unroll
        for (int m = 0; m < GROUPn; ++m) {
            int row = (g * GROUPn + m) * Ln + l;
            cnt += (lbl[row] != 0);
            pa[m] = palt[row];
        }
        if (cnt > 0 && cnt < GROUPn) {
            float af = (float)cnt * 0.25f;
            float denom = af * (1.0f - af);   // >= 0.1875; 0.01 clamp never binds
            float s = 0.0f;
            #pragma unroll
            for (int m = 0; m < GROUPn; ++m) { float d = pa[m] - af; s += d * d; }
            r2 += 0.25f * s / denom;
        }
    }

    // ---- Phase B: pairwise JS ----
    const int t = blockIdx.x;
    const bool active = (t < NPAIR);
    float js = 0.0f;
    float wpair = 0.0f;
    if (active) {
        // triangular decode: i = largest with off(i) = i*(63-i)/2 <= t
        int i = (int)floorf((63.0f - sqrtf(3969.0f - 8.0f * (float)t)) * 0.5f);
        if (i < 0) i = 0;
        while (i * (63 - i) / 2 > t) --i;
        while ((i + 1) * (63 - (i + 1)) / 2 <= t) ++i;
        int j = i + 1 + (t - i * (63 - i) / 2);

        // wpair = w_ij + w_ji, computed by wave 0 (thread 0 keeps it)
        if (threadIdx.x < 64) {
            int lane = threadIdx.x;
            float v = (lane < 32) ? __expf(-y_evo[i * Bn + lane])
                                  : __expf(-y_evo[j * Bn + (lane - 32)]);
            #pragma unroll
            for (int off = 16; off > 0; off >>= 1)
                v += __shfl_xor(v, off, 64);
            float si = __shfl(v, 0, 64);
            float sj = __shfl(v, 32, 64);
            wpair = __expf(-y_evo[i * Bn + j]) / (si + EPSf)
                  + __expf(-y_evo[j * Bn + i]) / (sj + EPSf);
        }

        const float4* pi = (const float4*)prob + i * Ln;
        const float4* pj = (const float4*)prob + j * Ln;
        const unsigned char* li = lbl + i * Ln;
        const unsigned char* lj = lbl + j * Ln;
        const float* Hi = H + i * Ln;
        const float* Hj = H + j * Ln;
        for (int l = threadIdx.x; l < Ln; l += NTHR) {
            if (li[l] == lj[l]) {
                float4 p = pi[l], q = pj[l];
                float s = Hi[l] + Hj[l];
                float a0 = p.x + q.x, a1 = p.y + q.y, a2 = p.z + q.z, a3 = p.w + q.w;
                s -= a0 * __logf(0.5f * a0 + JS_EPSf);
                s -= a1 * __logf(0.5f * a1 + JS_EPSf);
                s -= a2 * __logf(0.5f * a2 + JS_EPSf);
                s -= a3 * __logf(0.5f * a3 + JS_EPSf);
                js += 0.5f * s;
            }
        }
    }

    float s1 = blockReduceSum(ce, sm);
    __syncthreads();
    float s2 = blockReduceSum(r2, sm);
    __syncthreads();
    float s3 = blockReduceSum(js, sm);
    if (threadIdx.x == 0) {
        pce[t]  = s1;
        pr2[t]  = s2;
        pevo[t] = active ? wpair * s3 : 0.0f;
    }

    grid.sync();

    // ---- Phase C: block 0 final reduce + assemble ----
    if (blockIdx.x == 0) {
        float a = 0.0f, b = 0.0f, c = 0.0f;
        for (int idx = threadIdx.x; idx < NBLK; idx += NTHR) {
            a += pce[idx];
            b += pr2[idx];
            c += pevo[idx];
        }
        __syncthreads();
        a = blockReduceSum(a, sm);
        __syncthreads();
        b = blockReduceSum(b, sm);
        __syncthreads();
        c = blockReduceSum(c, sm);
        if (threadIdx.x == 0) {
            float r2_loss = -b * (float)GROUPn / (float)Bn;
            out[0] = a + r2_loss + c;
            out[1] = a;
            out[2] = r2_loss;
            out[3] = c;
        }
    }
}

extern "C" void kernel_launch(void* const* d_in, const int* in_sizes, int n_in,
                              void* d_out, int out_size, void* d_ws, size_t ws_size,
                              hipStream_t stream) {
    const float* logits = (const float*)d_in[0];
    const float* prob   = (const float*)d_in[1];
    const float* y_true = (const float*)d_in[2];
    const float* y_evo  = (const float*)d_in[3];
    float* out = (float*)d_out;

    char* ws = (char*)d_ws;
    float* H            = (float*)(ws);                         // 512 KB
    float* palt         = (float*)(ws + (size_t)512 * 1024);    // 512 KB
    unsigned char* lbl  = (unsigned char*)(ws + (size_t)1024 * 1024); // 128 KB
    float* pce          = (float*)(ws + (size_t)1160 * 1024);
    float* pr2          = pce + NBLK;
    float* pevo         = pr2 + NBLK;

    void* args[] = {
        (void*)&logits, (void*)&prob, (void*)&y_true, (void*)&y_evo,
        (void*)&H, (void*)&palt, (void*)&lbl,
        (void*)&pce, (void*)&pr2, (void*)&pevo, (void*)&out
    };
    hipLaunchCooperativeKernel(reinterpret_cast<void*>(imp_coop),
                               dim3(NBLK), dim3(NTHR), args, 0, stream);
}

// Round 4
// 24.398 us; speedup vs baseline: 4.8489x; 4.8489x over previous
//
#include <hip/hip_runtime.h>

#define Bn 32
#define Ln 4096
#define GROUPn 4
#define NFG (Bn / GROUPn)
#define EPSf 1e-8f
#define JS_EPSf 1e-7f
#define NPAIR 496            // 32*31/2
#define CHUNKS 4             // chunks per pair
#define CHUNKL (Ln / CHUNKS) // 1024 positions per chunk
#define NBLK (NPAIR * CHUNKS)// 1984 blocks, all active
#define NTHR 256

// Block-wide sum reduction. Valid result in thread 0. Uses sm[4].
// Caller must __syncthreads() between consecutive uses.
__device__ __forceinline__ float blockReduceSum(float v, float* sm) {
    #pragma unroll
    for (int off = 32; off > 0; off >>= 1)
        v += __shfl_down(v, off, 64);
    int lane = threadIdx.x & 63;
    int wid  = threadIdx.x >> 6;
    if (lane == 0) sm[wid] = v;
    __syncthreads();
    v = (threadIdx.x < (NTHR >> 6)) ? sm[threadIdx.x] : 0.0f;
    if (wid == 0) {
        #pragma unroll
        for (int off = 32; off > 0; off >>= 1)
            v += __shfl_down(v, off, 64);
    }
    return v;
}

__device__ __forceinline__ int argmax4(float4 y) {
    int lbl = 0; float best = y.x;
    if (y.y > best) { best = y.y; lbl = 1; }
    if (y.z > best) { best = y.z; lbl = 2; }
    if (y.w > best) { best = y.w; lbl = 3; }
    return lbl;
}

// 1984 blocks x 256 threads.
//  - Pair part: block b -> pair p = b>>2, chunk c = b&3; every block active.
//    js symmetry: sum_ij w_ij*js_ij = sum_{i<j} (w_ij+w_ji)*js_ij (diag 0).
//    Each chunk-block scales its own js partial by wpair (sum distributes).
//  - CE part: tid < B*L -> one row.
//  - R2 part: tid in [B*L, B*L + NFG*L) -> one item.
__global__ __launch_bounds__(NTHR) void imp_fused(
    const float* __restrict__ logits,
    const float* __restrict__ prob,
    const float* __restrict__ y_true,
    const float* __restrict__ y_evo,
    float* __restrict__ pce,
    float* __restrict__ pr2,
    float* __restrict__ pevo)
{
    __shared__ float sm[4];
    const int tid = blockIdx.x * NTHR + threadIdx.x;

    // ---- CE: one row per thread for tid < B*L ----
    float ce = 0.0f;
    if (tid < Bn * Ln) {
        float4 y = ((const float4*)y_true)[tid];
        float4 x = ((const float4*)logits)[tid];
        int l = argmax4(y);
        float mx = fmaxf(fmaxf(x.x, x.y), fmaxf(x.z, x.w));
        float se = __expf(x.x - mx) + __expf(x.y - mx) +
                   __expf(x.z - mx) + __expf(x.w - mx);
        float xl = (l == 0) ? x.x : (l == 1) ? x.y : (l == 2) ? x.z : x.w;
        ce = (mx + __logf(se)) - xl;   // -log_softmax(x)[label]
    }

    // ---- R2: one item per thread for the next NFG*L threads ----
    float r2 = 0.0f;
    {
        int idx = tid - Bn * Ln;
        if (idx >= 0 && idx < NFG * Ln) {
            int g = idx >> 12;          // / Ln
            int l = idx & (Ln - 1);
            int cnt = 0;
            float pa[GROUPn];
            #pragma unroll
            for (int m = 0; m < GROUPn; ++m) {
                int row = (g * GROUPn + m) * Ln + l;
                float4 y = ((const float4*)y_true)[row];
                cnt += (argmax4(y) != 0);
                float4 p = ((const float4*)prob)[row];
                pa[m] = p.y + p.z + p.w;
            }
            if (cnt > 0 && cnt < GROUPn) {
                float af = (float)cnt * 0.25f;
                float denom = af * (1.0f - af); // >= 0.1875; 0.01 clamp never binds
                float s = 0.0f;
                #pragma unroll
                for (int m = 0; m < GROUPn; ++m) { float d = pa[m] - af; s += d * d; }
                r2 = 0.25f * s / denom;
            }
        }
    }

    // ---- Pair JS: pair p = blockIdx.x>>2, chunk c = blockIdx.x&3 ----
    const int t = blockIdx.x >> 2;
    const int c = blockIdx.x & (CHUNKS - 1);
    // triangular decode: i = largest with off(i) = i*(63-i)/2 <= t
    int i = (int)floorf((63.0f - sqrtf(3969.0f - 8.0f * (float)t)) * 0.5f);
    if (i < 0) i = 0;
    while (i * (63 - i) / 2 > t) --i;
    while ((i + 1) * (63 - (i + 1)) / 2 <= t) ++i;
    int j = i + 1 + (t - i * (63 - i) / 2);

    // wpair = w_ij + w_ji (row-sum softmax weights), via one wave-64 reduce
    float wpair = 0.0f;
    if (threadIdx.x < 64) {
        int lane = threadIdx.x;
        float v = (lane < 32) ? __expf(-y_evo[i * Bn + lane])
                              : __expf(-y_evo[j * Bn + (lane - 32)]);
        #pragma unroll
        for (int off = 16; off > 0; off >>= 1)
            v += __shfl_xor(v, off, 64);
        float si = __shfl(v, 0, 64);
        float sj = __shfl(v, 32, 64);
        wpair = __expf(-y_evo[i * Bn + j]) / (si + EPSf)
              + __expf(-y_evo[j * Bn + i]) / (sj + EPSf);
    }

    const int l0 = c * CHUNKL;
    const float4* pi = (const float4*)prob   + i * Ln + l0;
    const float4* pj = (const float4*)prob   + j * Ln + l0;
    const float4* yi = (const float4*)y_true + i * Ln + l0;
    const float4* yj = (const float4*)y_true + j * Ln + l0;
    float js = 0.0f;
    #pragma unroll
    for (int it = 0; it < CHUNKL / NTHR; ++it) {
        int l = it * NTHR + threadIdx.x;
        float4 a = yi[l], b = yj[l];
        // exact one-hot rows: elementwise equality == label equality
        bool eq = (a.x == b.x) && (a.y == b.y) && (a.z == b.z) && (a.w == b.w);
        if (eq) {
            float4 p = pi[l], q = pj[l];
            float s = 0.0f;
            float a0 = p.x + q.x, a1 = p.y + q.y, a2 = p.z + q.z, a3 = p.w + q.w;
            s += p.x * __logf(p.x + JS_EPSf) + q.x * __logf(q.x + JS_EPSf)
               - a0 * __logf(0.5f * a0 + JS_EPSf);
            s += p.y * __logf(p.y + JS_EPSf) + q.y * __logf(q.y + JS_EPSf)
               - a1 * __logf(0.5f * a1 + JS_EPSf);
            s += p.z * __logf(p.z + JS_EPSf) + q.z * __logf(q.z + JS_EPSf)
               - a2 * __logf(0.5f * a2 + JS_EPSf);
            s += p.w * __logf(p.w + JS_EPSf) + q.w * __logf(q.w + JS_EPSf)
               - a3 * __logf(0.5f * a3 + JS_EPSf);
            js += 0.5f * s;
        }
    }

    float s1 = blockReduceSum(ce, sm);
    __syncthreads();
    float s2 = blockReduceSum(r2, sm);
    __syncthreads();
    float s3 = blockReduceSum(js, sm);
    if (threadIdx.x == 0) {
        pce[blockIdx.x]  = s1;
        pr2[blockIdx.x]  = s2;
        pevo[blockIdx.x] = wpair * s3;
    }
}

// Final reduction of 3 x NBLK partials + loss assembly. One block.
__global__ __launch_bounds__(NTHR) void imp_reduce(
    const float* __restrict__ pce,
    const float* __restrict__ pr2,
    const float* __restrict__ pevo,
    float* __restrict__ out)
{
    __shared__ float sm[4];
    float ce = 0.0f, r2 = 0.0f, evo = 0.0f;
    for (int idx = threadIdx.x; idx < NBLK; idx += NTHR) {
        ce  += pce[idx];
        r2  += pr2[idx];
        evo += pevo[idx];
    }
    ce = blockReduceSum(ce, sm);
    __syncthreads();
    r2 = blockReduceSum(r2, sm);
    __syncthreads();
    evo = blockReduceSum(evo, sm);
    if (threadIdx.x == 0) {
        float r2_loss = -r2 * (float)GROUPn / (float)Bn;
        out[0] = ce + r2_loss + evo;
        out[1] = ce;
        out[2] = r2_loss;
        out[3] = evo;
    }
}

extern "C" void kernel_launch(void* const* d_in, const int* in_sizes, int n_in,
                              void* d_out, int out_size, void* d_ws, size_t ws_size,
                              hipStream_t stream) {
    const float* logits = (const float*)d_in[0];
    const float* prob   = (const float*)d_in[1];
    const float* y_true = (const float*)d_in[2];
    const float* y_evo  = (const float*)d_in[3];
    float* out  = (float*)d_out;
    float* pce  = (float*)d_ws;
    float* pr2  = pce + NBLK;
    float* pevo = pr2 + NBLK;

    hipLaunchKernelGGL(imp_fused, dim3(NBLK), dim3(NTHR), 0, stream,
                       logits, prob, y_true, y_evo, pce, pr2, pevo);
    hipLaunchKernelGGL(imp_reduce, dim3(1), dim3(NTHR), 0, stream,
                       pce, pr2, pevo, out);
}